// Round 2
// baseline (14612.242 us; speedup 1.0000x reference)
//
#include <hip/hip_runtime.h>
#include <hip/hip_bf16.h>
#include <math.h>

#define S 2048
#define HID 1024
#define NH 8
#define HD 128
#define INTER 4096
#define EPSV 1e-6f
#define THETA 10000.0f

typedef __hip_bfloat16 bf16;

__device__ inline float b2f(bf16 v) { return __bfloat162float(v); }

// Dual-dtype input load: isbf ? bf16 : f32
__device__ inline float ldin(const void* p, size_t i, bool isbf) {
    return isbf ? __bfloat162float(((const bf16*)p)[i]) : ((const float*)p)[i];
}

__device__ inline float gelu_tanh(float x) {
    float x3 = x * x * x;
    return 0.5f * x * (1.f + tanhf(0.7978845608028654f * (x + 0.044715f * x3)));
}

// ---------------- dtype probe: examine even-indexed u16s of x_a ----------------
// bf16 data: even u16s are bf16 normals -> exponent field in [110,135] ~always.
// fp32 data: even u16s are low mantissa bits -> exponent field ~uniform (~10% in range).
__global__ __launch_bounds__(256) void probe_kernel(const unsigned short* __restrict__ x,
                                                    int* __restrict__ flag) {
    __shared__ int red[256];
    int tid = threadIdx.x;
    int cnt = 0;
    for (int i = tid; i < 2048; i += 256) {
        unsigned short u = x[2 * i];
        int e = (u >> 7) & 0xFF;
        cnt += (e >= 110 && e <= 135) ? 1 : 0;
    }
    red[tid] = cnt;
    __syncthreads();
    for (int off = 128; off > 0; off >>= 1) {
        if (tid < off) red[tid] += red[tid + off];
        __syncthreads();
    }
    if (tid == 0) *flag = (red[0] > 1024) ? 1 : 0;
}

// ---------------- RMSNorm: y = x * rsqrt(mean(x^2)+eps) * (1+w) ----------------
// dual=1: x is a raw input (dtype per *flag). dual=0: x is f32 workspace.
__global__ __launch_bounds__(256) void rmsnorm_kernel(const void* __restrict__ x,
                                                      const void* __restrict__ w,
                                                      float* __restrict__ y,
                                                      const int* __restrict__ flag,
                                                      int dual) {
    bool isbf = (*flag != 0);
    bool xbf = dual && isbf;
    int row = blockIdx.x;
    size_t base = (size_t)row * HID;
    __shared__ float red[256];
    float xv[4];
    float s = 0.f;
#pragma unroll
    for (int i = 0; i < 4; i++) {
        float v = ldin(x, base + threadIdx.x + 256 * i, xbf);
        xv[i] = v;
        s += v * v;
    }
    red[threadIdx.x] = s;
    __syncthreads();
    for (int off = 128; off > 0; off >>= 1) {
        if (threadIdx.x < off) red[threadIdx.x] += red[threadIdx.x + off];
        __syncthreads();
    }
    float scale = rsqrtf(red[0] / (float)HID + EPSV);
#pragma unroll
    for (int i = 0; i < 4; i++) {
        int c = threadIdx.x + 256 * i;
        y[base + c] = xv[i] * scale * (1.f + ldin(w, c, isbf));
    }
}

// ---------------- Generic GEMM: C = A(f32, MxK) @ B(input dtype, KxN) ----------------
// EPI 0: C = acc ; EPI 1: C = acc + residual(input dtype) ; EPI 2: C += acc
template <int EPI>
__global__ __launch_bounds__(256) void gemm_kernel(const float* __restrict__ A,
                                                   const void* __restrict__ B,
                                                   float* __restrict__ C,
                                                   const void* __restrict__ res,
                                                   const int* __restrict__ flag,
                                                   int M, int N, int K) {
    bool isbf = (*flag != 0);
    const int BM = 64, BN = 64, BK = 16;
    __shared__ float As[BK][BM];
    __shared__ float Bs[BK][BN];
    int tid = threadIdx.x;
    int tx = tid & 15, ty = tid >> 4;
    int m0 = blockIdx.y * BM, n0 = blockIdx.x * BN;
    float acc[4][4] = {};
    for (int k0 = 0; k0 < K; k0 += BK) {
#pragma unroll
        for (int i = 0; i < 4; i++) {
            int l = tid + 256 * i;
            int mm = l >> 4, kk = l & 15;
            As[kk][mm] = A[(size_t)(m0 + mm) * K + k0 + kk];
        }
        if (isbf) {
            const bf16* Bb = (const bf16*)B;
#pragma unroll
            for (int i = 0; i < 4; i++) {
                int l = tid + 256 * i;
                int kk = l >> 6, nn = l & 63;
                Bs[kk][nn] = b2f(Bb[(size_t)(k0 + kk) * N + n0 + nn]);
            }
        } else {
            const float* Bf = (const float*)B;
#pragma unroll
            for (int i = 0; i < 4; i++) {
                int l = tid + 256 * i;
                int kk = l >> 6, nn = l & 63;
                Bs[kk][nn] = Bf[(size_t)(k0 + kk) * N + n0 + nn];
            }
        }
        __syncthreads();
#pragma unroll
        for (int kk = 0; kk < BK; kk++) {
            float a_[4], b_[4];
#pragma unroll
            for (int i = 0; i < 4; i++) a_[i] = As[kk][ty * 4 + i];
#pragma unroll
            for (int j = 0; j < 4; j++) b_[j] = Bs[kk][tx * 4 + j];
#pragma unroll
            for (int i = 0; i < 4; i++)
#pragma unroll
                for (int j = 0; j < 4; j++) acc[i][j] += a_[i] * b_[j];
        }
        __syncthreads();
    }
#pragma unroll
    for (int i = 0; i < 4; i++) {
        int row = m0 + ty * 4 + i;
#pragma unroll
        for (int j = 0; j < 4; j++) {
            int col = n0 + tx * 4 + j;
            size_t idx = (size_t)row * N + col;
            float v = acc[i][j];
            if (EPI == 1) v += ldin(res, idx, isbf);
            if (EPI == 2) v += C[idx];
            C[idx] = v;
        }
    }
}

// ------------- Fused gated MLP GEMM: C = gelu(A@Bg) * (A@Bu) -------------
__global__ __launch_bounds__(256) void gemm_gated_kernel(const float* __restrict__ A,
                                                         const void* __restrict__ Bg,
                                                         const void* __restrict__ Bu,
                                                         float* __restrict__ C,
                                                         const int* __restrict__ flag,
                                                         int M, int N, int K) {
    bool isbf = (*flag != 0);
    const int BM = 64, BN = 64, BK = 16;
    __shared__ float As[BK][BM];
    __shared__ float Bgs[BK][BN];
    __shared__ float Bus[BK][BN];
    int tid = threadIdx.x;
    int tx = tid & 15, ty = tid >> 4;
    int m0 = blockIdx.y * BM, n0 = blockIdx.x * BN;
    float accg[4][4] = {};
    float accu[4][4] = {};
    for (int k0 = 0; k0 < K; k0 += BK) {
#pragma unroll
        for (int i = 0; i < 4; i++) {
            int l = tid + 256 * i;
            int mm = l >> 4, kk = l & 15;
            As[kk][mm] = A[(size_t)(m0 + mm) * K + k0 + kk];
        }
        if (isbf) {
            const bf16* Bgb = (const bf16*)Bg;
            const bf16* Bub = (const bf16*)Bu;
#pragma unroll
            for (int i = 0; i < 4; i++) {
                int l = tid + 256 * i;
                int kk = l >> 6, nn = l & 63;
                size_t gidx = (size_t)(k0 + kk) * N + n0 + nn;
                Bgs[kk][nn] = b2f(Bgb[gidx]);
                Bus[kk][nn] = b2f(Bub[gidx]);
            }
        } else {
            const float* Bgf = (const float*)Bg;
            const float* Buf = (const float*)Bu;
#pragma unroll
            for (int i = 0; i < 4; i++) {
                int l = tid + 256 * i;
                int kk = l >> 6, nn = l & 63;
                size_t gidx = (size_t)(k0 + kk) * N + n0 + nn;
                Bgs[kk][nn] = Bgf[gidx];
                Bus[kk][nn] = Buf[gidx];
            }
        }
        __syncthreads();
#pragma unroll
        for (int kk = 0; kk < BK; kk++) {
            float a_[4], bg_[4], bu_[4];
#pragma unroll
            for (int i = 0; i < 4; i++) a_[i] = As[kk][ty * 4 + i];
#pragma unroll
            for (int j = 0; j < 4; j++) {
                bg_[j] = Bgs[kk][tx * 4 + j];
                bu_[j] = Bus[kk][tx * 4 + j];
            }
#pragma unroll
            for (int i = 0; i < 4; i++)
#pragma unroll
                for (int j = 0; j < 4; j++) {
                    accg[i][j] += a_[i] * bg_[j];
                    accu[i][j] += a_[i] * bu_[j];
                }
        }
        __syncthreads();
    }
#pragma unroll
    for (int i = 0; i < 4; i++) {
        int row = m0 + ty * 4 + i;
#pragma unroll
        for (int j = 0; j < 4; j++) {
            int col = n0 + tx * 4 + j;
            C[(size_t)row * N + col] = gelu_tanh(accg[i][j]) * accu[i][j];
        }
    }
}

// ---------------- RoPE: per (t, head), pairs (i, i+64) ----------------
__global__ __launch_bounds__(64) void rope_kernel(const float* __restrict__ q,
                                                  const float* __restrict__ k,
                                                  float* __restrict__ qr,
                                                  float* __restrict__ kr) {
    int b = blockIdx.x;
    int t = b >> 3, h = b & 7;
    int i = threadIdx.x;  // 0..63
    size_t base = (size_t)t * HID + h * HD;
    float inv = powf(THETA, -(float)(2 * i) / (float)HD);
    float f = (float)t * inv;
    float c = cosf(f), s = sinf(f);
    float q1 = q[base + i], q2 = q[base + i + 64];
    qr[base + i] = q1 * c - q2 * s;
    qr[base + i + 64] = q2 * c + q1 * s;
    float k1 = k[base + i], k2 = k[base + i + 64];
    kr[base + i] = k1 * c - k2 * s;
    kr[base + i + 64] = k2 * c + k1 * s;
}

// ------------- Causal attention, one block per (query row, head) -------------
__global__ __launch_bounds__(128) void attn_causal_kernel(const float* __restrict__ Q,
                                                          const float* __restrict__ K,
                                                          const float* __restrict__ V,
                                                          float* __restrict__ O) {
    int r = blockIdx.x, h = blockIdx.y;
    int tid = threadIdx.x;
    __shared__ float qv[HD];
    __shared__ float sc[S];
    __shared__ float red[128];
    const float scale = 0.08838834764831845f;  // 1/sqrt(128)
    size_t hoff = (size_t)h * HD;
    qv[tid] = Q[(size_t)r * HID + hoff + tid];
    __syncthreads();
    int nk = r + 1;
    float mx = -1e30f;
    for (int j = tid; j < nk; j += 128) {
        const float4* k4 = reinterpret_cast<const float4*>(K + (size_t)j * HID + hoff);
        float s = 0.f;
#pragma unroll
        for (int d4 = 0; d4 < HD / 4; d4++) {
            float4 kv = k4[d4];
            s += qv[4 * d4] * kv.x + qv[4 * d4 + 1] * kv.y + qv[4 * d4 + 2] * kv.z +
                 qv[4 * d4 + 3] * kv.w;
        }
        s *= scale;
        sc[j] = s;
        mx = fmaxf(mx, s);
    }
    red[tid] = mx;
    __syncthreads();
    for (int off = 64; off > 0; off >>= 1) {
        if (tid < off) red[tid] = fmaxf(red[tid], red[tid + off]);
        __syncthreads();
    }
    mx = red[0];
    __syncthreads();
    float sum = 0.f;
    for (int j = tid; j < nk; j += 128) {
        float e = expf(sc[j] - mx);
        sc[j] = e;
        sum += e;
    }
    red[tid] = sum;
    __syncthreads();
    for (int off = 64; off > 0; off >>= 1) {
        if (tid < off) red[tid] += red[tid + off];
        __syncthreads();
    }
    float inv = 1.f / red[0];
    float acc = 0.f;
    const float* vp = V + hoff + tid;
    for (int j = 0; j < nk; j++) acc += sc[j] * vp[(size_t)j * HID];
    O[(size_t)r * HID + hoff + tid] = acc * inv;
}

// ------------- Mix attention: 4096 keys (a then b), no mask, pre-RoPE -------------
__global__ __launch_bounds__(128) void attn_mix_kernel(const float* __restrict__ qa,
                                                       const float* __restrict__ ka,
                                                       const float* __restrict__ va,
                                                       const float* __restrict__ qb,
                                                       const float* __restrict__ kb,
                                                       const float* __restrict__ vb,
                                                       float* __restrict__ O) {
    int r = blockIdx.x, h = blockIdx.y;
    int tid = threadIdx.x;
    __shared__ float qv[HD];
    __shared__ float sc[2 * S];
    __shared__ float red[128];
    const float scale = 0.08838834764831845f;
    size_t hoff = (size_t)h * HD;
    const float* qrow =
        (r < S ? qa + (size_t)r * HID : qb + (size_t)(r - S) * HID) + hoff;
    qv[tid] = qrow[tid];
    __syncthreads();
    float mx = -1e30f;
    for (int j = tid; j < 2 * S; j += 128) {
        const float* kp =
            (j < S ? ka + (size_t)j * HID : kb + (size_t)(j - S) * HID) + hoff;
        const float4* k4 = reinterpret_cast<const float4*>(kp);
        float s = 0.f;
#pragma unroll
        for (int d4 = 0; d4 < HD / 4; d4++) {
            float4 kv = k4[d4];
            s += qv[4 * d4] * kv.x + qv[4 * d4 + 1] * kv.y + qv[4 * d4 + 2] * kv.z +
                 qv[4 * d4 + 3] * kv.w;
        }
        s *= scale;
        sc[j] = s;
        mx = fmaxf(mx, s);
    }
    red[tid] = mx;
    __syncthreads();
    for (int off = 64; off > 0; off >>= 1) {
        if (tid < off) red[tid] = fmaxf(red[tid], red[tid + off]);
        __syncthreads();
    }
    mx = red[0];
    __syncthreads();
    float sum = 0.f;
    for (int j = tid; j < 2 * S; j += 128) {
        float e = expf(sc[j] - mx);
        sc[j] = e;
        sum += e;
    }
    red[tid] = sum;
    __syncthreads();
    for (int off = 64; off > 0; off >>= 1) {
        if (tid < off) red[tid] += red[tid + off];
        __syncthreads();
    }
    float inv = 1.f / red[0];
    float acc = 0.f;
    const float* vap = va + hoff + tid;
    const float* vbp = vb + hoff + tid;
    for (int j = 0; j < S; j++) acc += sc[j] * vap[(size_t)j * HID];
    for (int j = 0; j < S; j++) acc += sc[S + j] * vbp[(size_t)j * HID];
    O[(size_t)r * HID + hoff + tid] = acc * inv;
}

// ---------------- f32 -> output dtype (per flag) ----------------
__global__ __launch_bounds__(256) void store_out_kernel(const float* __restrict__ a,
                                                        const float* __restrict__ b,
                                                        void* __restrict__ out,
                                                        const int* __restrict__ flag) {
    bool isbf = (*flag != 0);
    size_t i = (size_t)blockIdx.x * 256 + threadIdx.x;
    const size_t MM = (size_t)S * HID;
    float v = (i < MM) ? a[i] : b[i - MM];
    if (isbf)
        ((bf16*)out)[i] = __float2bfloat16(v);
    else
        ((float*)out)[i] = v;
}

extern "C" void kernel_launch(void* const* d_in, const int* in_sizes, int n_in,
                              void* d_out, int out_size, void* d_ws, size_t ws_size,
                              hipStream_t stream) {
    // Input order: x_a, x_b, mask_a, mask_b, mix_mask,
    // then per expert: w_ln, w_q, w_k, w_v, w_o, w_pln, w_g, w_u, w_d
    const void* x[2] = {d_in[0], d_in[1]};
    const void* w_ln[2] = {d_in[5], d_in[14]};
    const void* w_q[2] = {d_in[6], d_in[15]};
    const void* w_k[2] = {d_in[7], d_in[16]};
    const void* w_v[2] = {d_in[8], d_in[17]};
    const void* w_o[2] = {d_in[9], d_in[18]};
    const void* w_pln[2] = {d_in[10], d_in[19]};
    const void* w_g[2] = {d_in[11], d_in[20]};
    const void* w_u[2] = {d_in[12], d_in[21]};
    const void* w_d[2] = {d_in[13], d_in[22]};

    int* flag = (int*)d_ws;
    float* ws = (float*)d_ws + 64;  // 256B header for the flag
    const size_t MM = (size_t)S * HID;  // 2M floats
    float* q[2] = {ws + 0 * MM, ws + 3 * MM};
    float* k[2] = {ws + 1 * MM, ws + 4 * MM};
    float* v[2] = {ws + 2 * MM, ws + 5 * MM};
    float* outX[2] = {ws + 6 * MM, ws + 7 * MM};
    float* h = ws + 8 * MM;
    float* qr = ws + 9 * MM;
    float* kr = ws + 10 * MM;
    float* attnbuf = ws + 11 * MM;
    float* gated = ws + 12 * MM;   // S*INTER = 4*MM floats
    float* mixed = ws + 12 * MM;   // 2*MM floats, overlays gated after it's dead

    dim3 gProj(HID / 64, S / 64);
    dim3 gMlpUp(INTER / 64, S / 64);

    probe_kernel<<<1, 256, 0, stream>>>((const unsigned short*)d_in[0], flag);

    for (int e = 0; e < 2; e++) {
        rmsnorm_kernel<<<S, 256, 0, stream>>>(x[e], w_ln[e], h, flag, 1);
        gemm_kernel<0><<<gProj, 256, 0, stream>>>(h, w_q[e], q[e], nullptr, flag, S, HID, HID);
        gemm_kernel<0><<<gProj, 256, 0, stream>>>(h, w_k[e], k[e], nullptr, flag, S, HID, HID);
        gemm_kernel<0><<<gProj, 256, 0, stream>>>(h, w_v[e], v[e], nullptr, flag, S, HID, HID);
        rope_kernel<<<S * NH, 64, 0, stream>>>(q[e], k[e], qr, kr);
        attn_causal_kernel<<<dim3(S, NH), 128, 0, stream>>>(qr, kr, v[e], attnbuf);
        gemm_kernel<1><<<gProj, 256, 0, stream>>>(attnbuf, w_o[e], outX[e], x[e], flag, S, HID, HID);
        rmsnorm_kernel<<<S, 256, 0, stream>>>(outX[e], w_pln[e], h, flag, 0);
        gemm_gated_kernel<<<gMlpUp, 256, 0, stream>>>(h, w_g[e], w_u[e], gated, flag, S, INTER, HID);
        gemm_kernel<2><<<gProj, 256, 0, stream>>>(gated, w_d[e], outX[e], nullptr, flag, S, HID, INTER);
    }

    attn_mix_kernel<<<dim3(2 * S, NH), 128, 0, stream>>>(q[0], k[0], v[0], q[1], k[1],
                                                         v[1], mixed);
    gemm_kernel<2><<<gProj, 256, 0, stream>>>(mixed, w_o[0], outX[0], nullptr, flag, S, HID, HID);
    gemm_kernel<2><<<gProj, 256, 0, stream>>>(mixed + MM, w_o[1], outX[1], nullptr, flag, S, HID, HID);

    store_out_kernel<<<(2 * MM) / 256, 256, 0, stream>>>(outX[0], outX[1], d_out, flag);
}

// Round 3
// 5444.302 us; speedup vs baseline: 2.6840x; 2.6840x over previous
//
#include <hip/hip_runtime.h>
#include <hip/hip_bf16.h>
#include <math.h>

#define S 2048
#define HID 1024
#define NH 8
#define HD 128
#define INTER 4096
#define EPSV 1e-6f
#define THETA 10000.0f

typedef __hip_bfloat16 bf16;

__device__ inline float b2f(bf16 v) { return __bfloat162float(v); }

// Dual-dtype input load: isbf ? bf16 : f32
__device__ inline float ldin(const void* p, size_t i, bool isbf) {
    return isbf ? __bfloat162float(((const bf16*)p)[i]) : ((const float*)p)[i];
}

__device__ inline float gelu_tanh(float x) {
    float x3 = x * x * x;
    return 0.5f * x * (1.f + tanhf(0.7978845608028654f * (x + 0.044715f * x3)));
}

// ---------------- dtype probe (see round 1 notes) ----------------
__global__ __launch_bounds__(256) void probe_kernel(const unsigned short* __restrict__ x,
                                                    int* __restrict__ flag) {
    __shared__ int red[256];
    int tid = threadIdx.x;
    int cnt = 0;
    for (int i = tid; i < 2048; i += 256) {
        unsigned short u = x[2 * i];
        int e = (u >> 7) & 0xFF;
        cnt += (e >= 110 && e <= 135) ? 1 : 0;
    }
    red[tid] = cnt;
    __syncthreads();
    for (int off = 128; off > 0; off >>= 1) {
        if (tid < off) red[tid] += red[tid + off];
        __syncthreads();
    }
    if (tid == 0) *flag = (red[0] > 1024) ? 1 : 0;
}

// ---------------- RMSNorm ----------------
__global__ __launch_bounds__(256) void rmsnorm_kernel(const void* __restrict__ x,
                                                      const void* __restrict__ w,
                                                      float* __restrict__ y,
                                                      const int* __restrict__ flag,
                                                      int dual) {
    bool isbf = (*flag != 0);
    bool xbf = dual && isbf;
    int row = blockIdx.x;
    size_t base = (size_t)row * HID;
    __shared__ float red[256];
    float xv[4];
    float s = 0.f;
#pragma unroll
    for (int i = 0; i < 4; i++) {
        float v = ldin(x, base + threadIdx.x + 256 * i, xbf);
        xv[i] = v;
        s += v * v;
    }
    red[threadIdx.x] = s;
    __syncthreads();
    for (int off = 128; off > 0; off >>= 1) {
        if (threadIdx.x < off) red[threadIdx.x] += red[threadIdx.x + off];
        __syncthreads();
    }
    float scale = rsqrtf(red[0] / (float)HID + EPSV);
#pragma unroll
    for (int i = 0; i < 4; i++) {
        int c = threadIdx.x + 256 * i;
        y[base + c] = xv[i] * scale * (1.f + ldin(w, c, isbf));
    }
}

// ---------------- Generic GEMM: C = A(f32) @ B(input dtype) ----------------
template <int EPI>
__global__ __launch_bounds__(256) void gemm_kernel(const float* __restrict__ A,
                                                   const void* __restrict__ B,
                                                   float* __restrict__ C,
                                                   const void* __restrict__ res,
                                                   const int* __restrict__ flag,
                                                   int M, int N, int K) {
    bool isbf = (*flag != 0);
    const int BM = 64, BN = 64, BK = 16;
    __shared__ float As[BK][BM];
    __shared__ float Bs[BK][BN];
    int tid = threadIdx.x;
    int tx = tid & 15, ty = tid >> 4;
    int m0 = blockIdx.y * BM, n0 = blockIdx.x * BN;
    float acc[4][4] = {};
    for (int k0 = 0; k0 < K; k0 += BK) {
#pragma unroll
        for (int i = 0; i < 4; i++) {
            int l = tid + 256 * i;
            int mm = l >> 4, kk = l & 15;
            As[kk][mm] = A[(size_t)(m0 + mm) * K + k0 + kk];
        }
        if (isbf) {
            const bf16* Bb = (const bf16*)B;
#pragma unroll
            for (int i = 0; i < 4; i++) {
                int l = tid + 256 * i;
                int kk = l >> 6, nn = l & 63;
                Bs[kk][nn] = b2f(Bb[(size_t)(k0 + kk) * N + n0 + nn]);
            }
        } else {
            const float* Bf = (const float*)B;
#pragma unroll
            for (int i = 0; i < 4; i++) {
                int l = tid + 256 * i;
                int kk = l >> 6, nn = l & 63;
                Bs[kk][nn] = Bf[(size_t)(k0 + kk) * N + n0 + nn];
            }
        }
        __syncthreads();
#pragma unroll
        for (int kk = 0; kk < BK; kk++) {
            float a_[4], b_[4];
#pragma unroll
            for (int i = 0; i < 4; i++) a_[i] = As[kk][ty * 4 + i];
#pragma unroll
            for (int j = 0; j < 4; j++) b_[j] = Bs[kk][tx * 4 + j];
#pragma unroll
            for (int i = 0; i < 4; i++)
#pragma unroll
                for (int j = 0; j < 4; j++) acc[i][j] += a_[i] * b_[j];
        }
        __syncthreads();
    }
#pragma unroll
    for (int i = 0; i < 4; i++) {
        int row = m0 + ty * 4 + i;
#pragma unroll
        for (int j = 0; j < 4; j++) {
            int col = n0 + tx * 4 + j;
            size_t idx = (size_t)row * N + col;
            float v = acc[i][j];
            if (EPI == 1) v += ldin(res, idx, isbf);
            if (EPI == 2) v += C[idx];
            C[idx] = v;
        }
    }
}

// ------------- Fused gated MLP GEMM: C = gelu(A@Bg) * (A@Bu) -------------
__global__ __launch_bounds__(256) void gemm_gated_kernel(const float* __restrict__ A,
                                                         const void* __restrict__ Bg,
                                                         const void* __restrict__ Bu,
                                                         float* __restrict__ C,
                                                         const int* __restrict__ flag,
                                                         int M, int N, int K) {
    bool isbf = (*flag != 0);
    const int BM = 64, BN = 64, BK = 16;
    __shared__ float As[BK][BM];
    __shared__ float Bgs[BK][BN];
    __shared__ float Bus[BK][BN];
    int tid = threadIdx.x;
    int tx = tid & 15, ty = tid >> 4;
    int m0 = blockIdx.y * BM, n0 = blockIdx.x * BN;
    float accg[4][4] = {};
    float accu[4][4] = {};
    for (int k0 = 0; k0 < K; k0 += BK) {
#pragma unroll
        for (int i = 0; i < 4; i++) {
            int l = tid + 256 * i;
            int mm = l >> 4, kk = l & 15;
            As[kk][mm] = A[(size_t)(m0 + mm) * K + k0 + kk];
        }
        if (isbf) {
            const bf16* Bgb = (const bf16*)Bg;
            const bf16* Bub = (const bf16*)Bu;
#pragma unroll
            for (int i = 0; i < 4; i++) {
                int l = tid + 256 * i;
                int kk = l >> 6, nn = l & 63;
                size_t gidx = (size_t)(k0 + kk) * N + n0 + nn;
                Bgs[kk][nn] = b2f(Bgb[gidx]);
                Bus[kk][nn] = b2f(Bub[gidx]);
            }
        } else {
            const float* Bgf = (const float*)Bg;
            const float* Buf = (const float*)Bu;
#pragma unroll
            for (int i = 0; i < 4; i++) {
                int l = tid + 256 * i;
                int kk = l >> 6, nn = l & 63;
                size_t gidx = (size_t)(k0 + kk) * N + n0 + nn;
                Bgs[kk][nn] = Bgf[gidx];
                Bus[kk][nn] = Buf[gidx];
            }
        }
        __syncthreads();
#pragma unroll
        for (int kk = 0; kk < BK; kk++) {
            float a_[4], bg_[4], bu_[4];
#pragma unroll
            for (int i = 0; i < 4; i++) a_[i] = As[kk][ty * 4 + i];
#pragma unroll
            for (int j = 0; j < 4; j++) {
                bg_[j] = Bgs[kk][tx * 4 + j];
                bu_[j] = Bus[kk][tx * 4 + j];
            }
#pragma unroll
            for (int i = 0; i < 4; i++)
#pragma unroll
                for (int j = 0; j < 4; j++) {
                    accg[i][j] += a_[i] * bg_[j];
                    accu[i][j] += a_[i] * bu_[j];
                }
        }
        __syncthreads();
    }
#pragma unroll
    for (int i = 0; i < 4; i++) {
        int row = m0 + ty * 4 + i;
#pragma unroll
        for (int j = 0; j < 4; j++) {
            int col = n0 + tx * 4 + j;
            C[(size_t)row * N + col] = gelu_tanh(accg[i][j]) * accu[i][j];
        }
    }
}

// ---------------- RoPE ----------------
__global__ __launch_bounds__(64) void rope_kernel(const float* __restrict__ q,
                                                  const float* __restrict__ k,
                                                  float* __restrict__ qr,
                                                  float* __restrict__ kr) {
    int b = blockIdx.x;
    int t = b >> 3, h = b & 7;
    int i = threadIdx.x;  // 0..63
    size_t base = (size_t)t * HID + h * HD;
    float inv = powf(THETA, -(float)(2 * i) / (float)HD);
    float f = (float)t * inv;
    float c = cosf(f), s = sinf(f);
    float q1 = q[base + i], q2 = q[base + i + 64];
    qr[base + i] = q1 * c - q2 * s;
    qr[base + i + 64] = q2 * c + q1 * s;
    float k1 = k[base + i], k2 = k[base + i + 64];
    kr[base + i] = k1 * c - k2 * s;
    kr[base + i + 64] = k2 * c + k1 * s;
}

// ============ Tiled flash-style attention ============
// Block: 64-query tile x one head. 256 threads = (tx 0..15, ty 0..15).
// Score tile 64x32: thread owns rows ty*4+i (i<4), cols tx*2+j (j<2).
// O tile 64x128: thread owns rows ty*4+i, cols tx*8+c (c<8).
// Row-softmax reductions: 16-lane shuffle (one row = lanes of equal ty, same wave).
// LDS (padded for conflict-free float4/float2 reads):
//   QsT[d][r]: 128 x 68, KsT[d][c]: 128 x 36, Vs[j][d]: 32 x 132, PsT[j][r]: 32 x 68
template <bool CAUSAL>
__global__ __launch_bounds__(256) void attn_tiled_kernel(const float* __restrict__ qa,
                                                         const float* __restrict__ qb,
                                                         const float* __restrict__ ka,
                                                         const float* __restrict__ kb,
                                                         const float* __restrict__ va,
                                                         const float* __restrict__ vb,
                                                         float* __restrict__ Out,
                                                         int nkeys) {
    const int BQ = 64, BK = 32;
    const int QP = 68, KP = 36, VP = 132, PP = 68;
    __shared__ float QsT[HD * QP];
    __shared__ float KsT[HD * KP];
    __shared__ float Vs[BK * VP];
    __shared__ float PsT[BK * PP];

    int tid = threadIdx.x;
    int tx = tid & 15, ty = tid >> 4;
    int q0 = blockIdx.x * BQ;
    int h = blockIdx.y;
    const float scale = 0.08838834764831845f;  // 1/sqrt(128)

    // ---- stage Q tile transposed (once) ----
    const float* qbase =
        ((CAUSAL || q0 < S) ? qa + (size_t)q0 * HID : qb + (size_t)(q0 - S) * HID) +
        (size_t)h * HD;
#pragma unroll
    for (int it = 0; it < 8; it++) {
        int l = tid + 256 * it;   // 0..2047
        int row = l >> 5;         // 0..63
        int d4 = l & 31;
        float4 v = *reinterpret_cast<const float4*>(qbase + (size_t)row * HID + 4 * d4);
        QsT[(4 * d4 + 0) * QP + row] = v.x;
        QsT[(4 * d4 + 1) * QP + row] = v.y;
        QsT[(4 * d4 + 2) * QP + row] = v.z;
        QsT[(4 * d4 + 3) * QP + row] = v.w;
    }

    float o_[4][8];
    float m_[4], l_[4];
#pragma unroll
    for (int i = 0; i < 4; i++) {
        m_[i] = -1e30f;
        l_[i] = 0.f;
#pragma unroll
        for (int c = 0; c < 8; c++) o_[i][c] = 0.f;
    }

    int ntiles = CAUSAL ? (q0 >> 5) + 2 : (nkeys >> 5);

    for (int t = 0; t < ntiles; t++) {
        int j0 = t * BK;
        __syncthreads();  // prev PV done reading Vs/PsT; Q staged (first iter)
        // ---- stage K (transposed) and V tiles ----
        const float* kbase =
            ((CAUSAL || j0 < S) ? ka + (size_t)j0 * HID : kb + (size_t)(j0 - S) * HID) +
            (size_t)h * HD;
        const float* vbase =
            ((CAUSAL || j0 < S) ? va + (size_t)j0 * HID : vb + (size_t)(j0 - S) * HID) +
            (size_t)h * HD;
#pragma unroll
        for (int it = 0; it < 4; it++) {
            int l = tid + 256 * it;  // 0..1023
            int row = l >> 5;        // 0..31
            int d4 = l & 31;
            float4 kv = *reinterpret_cast<const float4*>(kbase + (size_t)row * HID + 4 * d4);
            KsT[(4 * d4 + 0) * KP + row] = kv.x;
            KsT[(4 * d4 + 1) * KP + row] = kv.y;
            KsT[(4 * d4 + 2) * KP + row] = kv.z;
            KsT[(4 * d4 + 3) * KP + row] = kv.w;
            float4 vv = *reinterpret_cast<const float4*>(vbase + (size_t)row * HID + 4 * d4);
            *reinterpret_cast<float4*>(&Vs[row * VP + 4 * d4]) = vv;
        }
        __syncthreads();

        // ---- QK^T: 4x2 scores per thread ----
        float s_[4][2] = {};
#pragma unroll 4
        for (int d = 0; d < HD; d++) {
            float4 aa = *reinterpret_cast<const float4*>(&QsT[d * QP + ty * 4]);
            float2 bb = *reinterpret_cast<const float2*>(&KsT[d * KP + tx * 2]);
            s_[0][0] += aa.x * bb.x; s_[0][1] += aa.x * bb.y;
            s_[1][0] += aa.y * bb.x; s_[1][1] += aa.y * bb.y;
            s_[2][0] += aa.z * bb.x; s_[2][1] += aa.z * bb.y;
            s_[3][0] += aa.w * bb.x; s_[3][1] += aa.w * bb.y;
        }
        bool diag = CAUSAL && (j0 + BK - 1 > q0);
#pragma unroll
        for (int i = 0; i < 4; i++) {
            int qi = q0 + ty * 4 + i;
#pragma unroll
            for (int j = 0; j < 2; j++) {
                float v = s_[i][j] * scale;
                if (diag && (j0 + tx * 2 + j > qi)) v = -1e30f;
                s_[i][j] = v;
            }
        }

        // ---- online softmax (per row: 16-lane butterfly) ----
        float alpha[4];
#pragma unroll
        for (int i = 0; i < 4; i++) {
            float rmax = fmaxf(s_[i][0], s_[i][1]);
#pragma unroll
            for (int mlane = 1; mlane < 16; mlane <<= 1)
                rmax = fmaxf(rmax, __shfl_xor(rmax, mlane));
            float mn = fmaxf(m_[i], rmax);
            float al = __expf(m_[i] - mn);
            float p0 = __expf(s_[i][0] - mn);
            float p1 = __expf(s_[i][1] - mn);
            float rs = p0 + p1;
#pragma unroll
            for (int mlane = 1; mlane < 16; mlane <<= 1) rs += __shfl_xor(rs, mlane);
            l_[i] = l_[i] * al + rs;
            m_[i] = mn;
            alpha[i] = al;
            PsT[(tx * 2 + 0) * PP + ty * 4 + i] = p0;
            PsT[(tx * 2 + 1) * PP + ty * 4 + i] = p1;
        }
        __syncthreads();

        // ---- PV accumulate: O = alpha*O + P@V ----
#pragma unroll
        for (int i = 0; i < 4; i++)
#pragma unroll
            for (int c = 0; c < 8; c++) o_[i][c] *= alpha[i];
#pragma unroll 2
        for (int j = 0; j < BK; j++) {
            float4 p4 = *reinterpret_cast<const float4*>(&PsT[j * PP + ty * 4]);
            float4 v0 = *reinterpret_cast<const float4*>(&Vs[j * VP + tx * 8]);
            float4 v1 = *reinterpret_cast<const float4*>(&Vs[j * VP + tx * 8 + 4]);
            float p_[4] = {p4.x, p4.y, p4.z, p4.w};
#pragma unroll
            for (int i = 0; i < 4; i++) {
                o_[i][0] += p_[i] * v0.x; o_[i][1] += p_[i] * v0.y;
                o_[i][2] += p_[i] * v0.z; o_[i][3] += p_[i] * v0.w;
                o_[i][4] += p_[i] * v1.x; o_[i][5] += p_[i] * v1.y;
                o_[i][6] += p_[i] * v1.z; o_[i][7] += p_[i] * v1.w;
            }
        }
    }

    // ---- finalize: O /= l, write out ----
#pragma unroll
    for (int i = 0; i < 4; i++) {
        float inv = 1.f / l_[i];
        size_t base = (size_t)(q0 + ty * 4 + i) * HID + (size_t)h * HD + tx * 8;
        float4 r0 = make_float4(o_[i][0] * inv, o_[i][1] * inv, o_[i][2] * inv, o_[i][3] * inv);
        float4 r1 = make_float4(o_[i][4] * inv, o_[i][5] * inv, o_[i][6] * inv, o_[i][7] * inv);
        *reinterpret_cast<float4*>(Out + base) = r0;
        *reinterpret_cast<float4*>(Out + base + 4) = r1;
    }
}

// ---------------- f32 -> output dtype (per flag) ----------------
__global__ __launch_bounds__(256) void store_out_kernel(const float* __restrict__ a,
                                                        const float* __restrict__ b,
                                                        void* __restrict__ out,
                                                        const int* __restrict__ flag) {
    bool isbf = (*flag != 0);
    size_t i = (size_t)blockIdx.x * 256 + threadIdx.x;
    const size_t MM = (size_t)S * HID;
    float v = (i < MM) ? a[i] : b[i - MM];
    if (isbf)
        ((bf16*)out)[i] = __float2bfloat16(v);
    else
        ((float*)out)[i] = v;
}

extern "C" void kernel_launch(void* const* d_in, const int* in_sizes, int n_in,
                              void* d_out, int out_size, void* d_ws, size_t ws_size,
                              hipStream_t stream) {
    const void* x[2] = {d_in[0], d_in[1]};
    const void* w_ln[2] = {d_in[5], d_in[14]};
    const void* w_q[2] = {d_in[6], d_in[15]};
    const void* w_k[2] = {d_in[7], d_in[16]};
    const void* w_v[2] = {d_in[8], d_in[17]};
    const void* w_o[2] = {d_in[9], d_in[18]};
    const void* w_pln[2] = {d_in[10], d_in[19]};
    const void* w_g[2] = {d_in[11], d_in[20]};
    const void* w_u[2] = {d_in[12], d_in[21]};
    const void* w_d[2] = {d_in[13], d_in[22]};

    int* flag = (int*)d_ws;
    float* ws = (float*)d_ws + 64;      // 256B header for the flag
    const size_t MM = (size_t)S * HID;  // 2M floats
    float* q[2] = {ws + 0 * MM, ws + 3 * MM};
    float* k[2] = {ws + 1 * MM, ws + 4 * MM};
    float* v[2] = {ws + 2 * MM, ws + 5 * MM};
    float* outX[2] = {ws + 6 * MM, ws + 7 * MM};
    float* h = ws + 8 * MM;
    float* qr = ws + 9 * MM;
    float* kr = ws + 10 * MM;
    float* attnbuf = ws + 11 * MM;
    float* gated = ws + 12 * MM;  // S*INTER = 4*MM floats
    float* mixed = ws + 12 * MM;  // 2*MM floats, overlays gated after it's dead

    dim3 gProj(HID / 64, S / 64);
    dim3 gMlpUp(INTER / 64, S / 64);

    probe_kernel<<<1, 256, 0, stream>>>((const unsigned short*)d_in[0], flag);

    for (int e = 0; e < 2; e++) {
        rmsnorm_kernel<<<S, 256, 0, stream>>>(x[e], w_ln[e], h, flag, 1);
        gemm_kernel<0><<<gProj, 256, 0, stream>>>(h, w_q[e], q[e], nullptr, flag, S, HID, HID);
        gemm_kernel<0><<<gProj, 256, 0, stream>>>(h, w_k[e], k[e], nullptr, flag, S, HID, HID);
        gemm_kernel<0><<<gProj, 256, 0, stream>>>(h, w_v[e], v[e], nullptr, flag, S, HID, HID);
        rope_kernel<<<S * NH, 64, 0, stream>>>(q[e], k[e], qr, kr);
        attn_tiled_kernel<true><<<dim3(S / 64, NH), 256, 0, stream>>>(
            qr, qr, kr, kr, v[e], v[e], attnbuf, S);
        gemm_kernel<1><<<gProj, 256, 0, stream>>>(attnbuf, w_o[e], outX[e], x[e], flag, S, HID, HID);
        rmsnorm_kernel<<<S, 256, 0, stream>>>(outX[e], w_pln[e], h, flag, 0);
        gemm_gated_kernel<<<gMlpUp, 256, 0, stream>>>(h, w_g[e], w_u[e], gated, flag, S, INTER, HID);
        gemm_kernel<2><<<gProj, 256, 0, stream>>>(gated, w_d[e], outX[e], nullptr, flag, S, HID, INTER);
    }

    attn_tiled_kernel<false><<<dim3(2 * S / 64, NH), 256, 0, stream>>>(
        q[0], q[1], k[0], k[1], v[0], v[1], mixed, 2 * S);
    gemm_kernel<2><<<gProj, 256, 0, stream>>>(mixed, w_o[0], outX[0], nullptr, flag, S, HID, HID);
    gemm_kernel<2><<<gProj, 256, 0, stream>>>(mixed + MM, w_o[1], outX[1], nullptr, flag, S, HID, HID);

    store_out_kernel<<<(2 * MM) / 256, 256, 0, stream>>>(outX[0], outX[1], d_out, flag);
}

// Round 4
// 2997.601 us; speedup vs baseline: 4.8746x; 1.8162x over previous
//
#include <hip/hip_runtime.h>
#include <hip/hip_bf16.h>
#include <math.h>

#define S 2048
#define HID 1024
#define NH 8
#define HD 128
#define INTER 4096
#define EPSV 1e-6f
#define THETA 10000.0f

typedef __hip_bfloat16 bf16;
typedef unsigned short u16;
typedef __attribute__((ext_vector_type(8))) short bf16x8;  // 8 bf16 = 4 VGPRs
typedef __attribute__((ext_vector_type(4))) float f32x4;

__device__ inline float bu2f(u16 u) {
    unsigned int x = ((unsigned int)u) << 16;
    return __uint_as_float(x);
}
__device__ inline u16 f2bu(float f) {
    bf16 h = __float2bfloat16(f);
    return *reinterpret_cast<u16*>(&h);
}
// Dual-dtype input load (raw harness inputs): isbf ? bf16 : f32
__device__ inline float ldin(const void* p, size_t i, bool isbf) {
    return isbf ? bu2f(((const u16*)p)[i]) : ((const float*)p)[i];
}
__device__ inline float gelu_tanh(float x) {
    float x3 = x * x * x;
    return 0.5f * x * (1.f + tanhf(0.7978845608028654f * (x + 0.044715f * x3)));
}

// ---------------- dtype probe (round-1 notes; detected fp32 on this harness) ----------------
__global__ __launch_bounds__(256) void probe_kernel(const unsigned short* __restrict__ x,
                                                    int* __restrict__ flag) {
    __shared__ int red[256];
    int tid = threadIdx.x;
    int cnt = 0;
    for (int i = tid; i < 2048; i += 256) {
        unsigned short u = x[2 * i];
        int e = (u >> 7) & 0xFF;
        cnt += (e >= 110 && e <= 135) ? 1 : 0;
    }
    red[tid] = cnt;
    __syncthreads();
    for (int off = 128; off > 0; off >>= 1) {
        if (tid < off) red[tid] += red[tid + off];
        __syncthreads();
    }
    if (tid == 0) *flag = (red[0] > 1024) ? 1 : 0;
}

// ---------------- weight transpose+convert: W (KxN, input dtype) -> WT (NxK, bf16) ----------------
__global__ __launch_bounds__(256) void transpose_w(const void* __restrict__ W,
                                                   u16* __restrict__ WT,
                                                   const int* __restrict__ flag,
                                                   int K, int N) {
    bool isbf = (*flag != 0);
    __shared__ float t[32][33];
    int n0 = blockIdx.x * 32, k0 = blockIdx.y * 32;
    int c = threadIdx.x & 31, r = threadIdx.x >> 5;
#pragma unroll
    for (int p = 0; p < 4; p++)
        t[r + 8 * p][c] = ldin(W, (size_t)(k0 + r + 8 * p) * N + n0 + c, isbf);
    __syncthreads();
#pragma unroll
    for (int p = 0; p < 4; p++) {
        int row = r + 8 * p;
        WT[(size_t)(n0 + row) * K + k0 + c] = f2bu(t[c][row]);
    }
}

// ---------------- RMSNorm -> bf16 ----------------
__global__ __launch_bounds__(256) void rmsnorm_kernel(const void* __restrict__ x,
                                                      const void* __restrict__ w,
                                                      u16* __restrict__ y,
                                                      const int* __restrict__ flag,
                                                      int dual) {
    bool isbf = (*flag != 0);
    bool xbf = dual && isbf;
    int row = blockIdx.x;
    size_t base = (size_t)row * HID;
    __shared__ float red[256];
    float xv[4];
    float s = 0.f;
#pragma unroll
    for (int i = 0; i < 4; i++) {
        float v = ldin(x, base + threadIdx.x + 256 * i, xbf);
        xv[i] = v;
        s += v * v;
    }
    red[threadIdx.x] = s;
    __syncthreads();
    for (int off = 128; off > 0; off >>= 1) {
        if (threadIdx.x < off) red[threadIdx.x] += red[threadIdx.x + off];
        __syncthreads();
    }
    float scale = rsqrtf(red[0] / (float)HID + EPSV);
#pragma unroll
    for (int i = 0; i < 4; i++) {
        int c = threadIdx.x + 256 * i;
        y[base + c] = f2bu(xv[i] * scale * (1.f + ldin(w, c, isbf)));
    }
}

// ================= MFMA GEMM =================
// C(MxN) = A(MxK bf16, row-major) @ B, with BT = B^T (NxK bf16, row-major).
// Per-wave 16x16x32 MFMA; lane mapping (guide-verified):
//   a-frag: A[m=lane&15][k=quad*8+j], b-frag: B[k=quad*8+j][n=lane&15] = BT[n][k..k+8)
//   c/d:    row = quad*4+reg, col = lane&15
// Block 256 thr = 4 waves arranged WRN x WCN; wave tile (BM/WRN)x(BN/WCN).
// EPI 0: Cb(bf16) = acc ; EPI 1: Cf(f32) = acc + res(input dtype) ; EPI 2: Cf += acc
template <int BM, int BN, int WRN, int WCN, int EPI>
__global__ __launch_bounds__(256) void gemm_mfma(const u16* __restrict__ A,
                                                 const u16* __restrict__ BT,
                                                 float* __restrict__ Cf,
                                                 u16* __restrict__ Cb,
                                                 const void* __restrict__ res,
                                                 const int* __restrict__ flag,
                                                 int M, int N, int K) {
    constexpr int BK = 32, LDK = 40;  // 80B row stride: 16B-aligned, odd-dword -> ~conflict-free
    constexpr int WM = BM / WRN, WN = BN / WCN, TI = WM / 16, TJ = WN / 16;
    constexpr int AIT = BM / 64, BIT = BN / 64;
    __shared__ u16 As[BM * LDK];
    __shared__ u16 Bs[BN * LDK];
    int tid = threadIdx.x, lane = tid & 63, wv = tid >> 6;
    int wr = wv / WCN, wc = wv % WCN;
    int m = lane & 15, quad = lane >> 4;
    int m0 = blockIdx.y * BM, n0 = blockIdx.x * BN;
    f32x4 acc[TI][TJ] = {};
    for (int k0 = 0; k0 < K; k0 += BK) {
        __syncthreads();
#pragma unroll
        for (int i = 0; i < AIT; i++) {
            int l = tid + 256 * i;
            int row = l >> 2, kq = l & 3;
            *reinterpret_cast<uint4*>(&As[row * LDK + kq * 8]) =
                *reinterpret_cast<const uint4*>(&A[(size_t)(m0 + row) * K + k0 + kq * 8]);
        }
#pragma unroll
        for (int i = 0; i < BIT; i++) {
            int l = tid + 256 * i;
            int row = l >> 2, kq = l & 3;
            *reinterpret_cast<uint4*>(&Bs[row * LDK + kq * 8]) =
                *reinterpret_cast<const uint4*>(&BT[(size_t)(n0 + row) * K + k0 + kq * 8]);
        }
        __syncthreads();
        bf16x8 af[TI], bf_[TJ];
#pragma unroll
        for (int i = 0; i < TI; i++)
            af[i] = *reinterpret_cast<const bf16x8*>(&As[(wr * WM + i * 16 + m) * LDK + quad * 8]);
#pragma unroll
        for (int j = 0; j < TJ; j++)
            bf_[j] = *reinterpret_cast<const bf16x8*>(&Bs[(wc * WN + j * 16 + m) * LDK + quad * 8]);
#pragma unroll
        for (int i = 0; i < TI; i++)
#pragma unroll
            for (int j = 0; j < TJ; j++)
                acc[i][j] = __builtin_amdgcn_mfma_f32_16x16x32_bf16(af[i], bf_[j], acc[i][j], 0, 0, 0);
    }
    bool isbf = (EPI == 1) ? (*flag != 0) : false;
#pragma unroll
    for (int i = 0; i < TI; i++) {
#pragma unroll
        for (int j = 0; j < TJ; j++) {
#pragma unroll
            for (int r = 0; r < 4; r++) {
                int row = m0 + wr * WM + i * 16 + quad * 4 + r;
                int col = n0 + wc * WN + j * 16 + m;
                size_t idx = (size_t)row * N + col;
                float v = acc[i][j][r];
                if (EPI == 0) Cb[idx] = f2bu(v);
                else if (EPI == 1) Cf[idx] = v + ldin(res, idx, isbf);
                else Cf[idx] = Cf[idx] + v;
            }
        }
    }
}

// ------------- Fused gated MLP MFMA: C(bf16) = gelu(A@Wg) * (A@Wu) -------------
template <int BM, int BN, int WRN, int WCN>
__global__ __launch_bounds__(256) void gemm_gated_mfma(const u16* __restrict__ A,
                                                       const u16* __restrict__ BgT,
                                                       const u16* __restrict__ BuT,
                                                       u16* __restrict__ C,
                                                       int M, int N, int K) {
    constexpr int BK = 32, LDK = 40;
    constexpr int WM = BM / WRN, WN = BN / WCN, TI = WM / 16, TJ = WN / 16;
    constexpr int AIT = BM / 64, BIT = BN / 64;
    __shared__ u16 As[BM * LDK];
    __shared__ u16 Bgs[BN * LDK];
    __shared__ u16 Bus[BN * LDK];
    int tid = threadIdx.x, lane = tid & 63, wv = tid >> 6;
    int wr = wv / WCN, wc = wv % WCN;
    int m = lane & 15, quad = lane >> 4;
    int m0 = blockIdx.y * BM, n0 = blockIdx.x * BN;
    f32x4 accg[TI][TJ] = {};
    f32x4 accu[TI][TJ] = {};
    for (int k0 = 0; k0 < K; k0 += BK) {
        __syncthreads();
#pragma unroll
        for (int i = 0; i < AIT; i++) {
            int l = tid + 256 * i;
            int row = l >> 2, kq = l & 3;
            *reinterpret_cast<uint4*>(&As[row * LDK + kq * 8]) =
                *reinterpret_cast<const uint4*>(&A[(size_t)(m0 + row) * K + k0 + kq * 8]);
        }
#pragma unroll
        for (int i = 0; i < BIT; i++) {
            int l = tid + 256 * i;
            int row = l >> 2, kq = l & 3;
            *reinterpret_cast<uint4*>(&Bgs[row * LDK + kq * 8]) =
                *reinterpret_cast<const uint4*>(&BgT[(size_t)(n0 + row) * K + k0 + kq * 8]);
            *reinterpret_cast<uint4*>(&Bus[row * LDK + kq * 8]) =
                *reinterpret_cast<const uint4*>(&BuT[(size_t)(n0 + row) * K + k0 + kq * 8]);
        }
        __syncthreads();
        bf16x8 af[TI], bg[TJ], bu[TJ];
#pragma unroll
        for (int i = 0; i < TI; i++)
            af[i] = *reinterpret_cast<const bf16x8*>(&As[(wr * WM + i * 16 + m) * LDK + quad * 8]);
#pragma unroll
        for (int j = 0; j < TJ; j++) {
            bg[j] = *reinterpret_cast<const bf16x8*>(&Bgs[(wc * WN + j * 16 + m) * LDK + quad * 8]);
            bu[j] = *reinterpret_cast<const bf16x8*>(&Bus[(wc * WN + j * 16 + m) * LDK + quad * 8]);
        }
#pragma unroll
        for (int i = 0; i < TI; i++)
#pragma unroll
            for (int j = 0; j < TJ; j++) {
                accg[i][j] = __builtin_amdgcn_mfma_f32_16x16x32_bf16(af[i], bg[j], accg[i][j], 0, 0, 0);
                accu[i][j] = __builtin_amdgcn_mfma_f32_16x16x32_bf16(af[i], bu[j], accu[i][j], 0, 0, 0);
            }
    }
#pragma unroll
    for (int i = 0; i < TI; i++)
#pragma unroll
        for (int j = 0; j < TJ; j++)
#pragma unroll
            for (int r = 0; r < 4; r++) {
                int row = m0 + wr * WM + i * 16 + quad * 4 + r;
                int col = n0 + wc * WN + j * 16 + m;
                C[(size_t)row * N + col] = f2bu(gelu_tanh(accg[i][j][r]) * accu[i][j][r]);
            }
}

// ---------------- RoPE: read qkv (bf16, stride 3072), write qr/kr (bf16, stride 1024) ----------------
__global__ __launch_bounds__(64) void rope_kernel(const u16* __restrict__ qkv,
                                                  u16* __restrict__ qr,
                                                  u16* __restrict__ kr) {
    int b = blockIdx.x;
    int t = b >> 3, h = b & 7;
    int i = threadIdx.x;  // 0..63
    size_t ib = (size_t)t * 3072 + h * HD;
    size_t ob = (size_t)t * HID + h * HD;
    float inv = powf(THETA, -(float)(2 * i) / (float)HD);
    float f = (float)t * inv;
    float c = cosf(f), s = sinf(f);
    float q1 = bu2f(qkv[ib + i]), q2 = bu2f(qkv[ib + i + 64]);
    qr[ob + i] = f2bu(q1 * c - q2 * s);
    qr[ob + i + 64] = f2bu(q2 * c + q1 * s);
    float k1 = bu2f(qkv[ib + 1024 + i]), k2 = bu2f(qkv[ib + 1024 + i + 64]);
    kr[ob + i] = f2bu(k1 * c - k2 * s);
    kr[ob + i + 64] = f2bu(k2 * c + k1 * s);
}

// ============ Tiled flash-style attention (bf16 in/out, f32 math) ============
// Conflict fixes this round: P written as float4 (was 8x scalar 8-way), V cols
// remapped to stride-4 pairs (tx*4, 64+tx*4) so Vs reads are ~minimal-cycle.
template <bool CAUSAL>
__global__ __launch_bounds__(256) void attn_tiled_kernel(
    const u16* __restrict__ qa, const u16* __restrict__ qb, int sq,
    const u16* __restrict__ ka, const u16* __restrict__ kb, int sk,
    const u16* __restrict__ va, const u16* __restrict__ vb, int sv,
    u16* __restrict__ Out, int nkeys) {
    const int BQ = 64, BK = 32;
    const int QP = 68, KP = 36, VP = 132, PP = 68;
    __shared__ float QsT[HD * QP];
    __shared__ float KsT[HD * KP];
    __shared__ float Vs[BK * VP];
    __shared__ float PsT[BK * PP];

    int tid = threadIdx.x;
    int tx = tid & 15, ty = tid >> 4;
    int q0 = blockIdx.x * BQ;
    int h = blockIdx.y;
    const float scale = 0.08838834764831845f;  // 1/sqrt(128)

    const u16* qbase =
        ((CAUSAL || q0 < S) ? qa + (size_t)q0 * sq : qb + (size_t)(q0 - S) * sq) +
        (size_t)h * HD;
#pragma unroll
    for (int it = 0; it < 8; it++) {
        int l = tid + 256 * it;  // 0..2047
        int row = l >> 5;        // 0..63
        int d4 = l & 31;
        ushort4 u = *reinterpret_cast<const ushort4*>(qbase + (size_t)row * sq + 4 * d4);
        QsT[(4 * d4 + 0) * QP + row] = bu2f(u.x);
        QsT[(4 * d4 + 1) * QP + row] = bu2f(u.y);
        QsT[(4 * d4 + 2) * QP + row] = bu2f(u.z);
        QsT[(4 * d4 + 3) * QP + row] = bu2f(u.w);
    }

    float o_[4][8];
    float m_[4], l_[4];
#pragma unroll
    for (int i = 0; i < 4; i++) {
        m_[i] = -1e30f;
        l_[i] = 0.f;
#pragma unroll
        for (int c = 0; c < 8; c++) o_[i][c] = 0.f;
    }

    int ntiles = CAUSAL ? (q0 >> 5) + 2 : (nkeys >> 5);

    for (int t = 0; t < ntiles; t++) {
        int j0 = t * BK;
        __syncthreads();
        const u16* kbase =
            ((CAUSAL || j0 < S) ? ka + (size_t)j0 * sk : kb + (size_t)(j0 - S) * sk) +
            (size_t)h * HD;
        const u16* vbase =
            ((CAUSAL || j0 < S) ? va + (size_t)j0 * sv : vb + (size_t)(j0 - S) * sv) +
            (size_t)h * HD;
#pragma unroll
        for (int it = 0; it < 4; it++) {
            int l = tid + 256 * it;  // 0..1023
            int row = l >> 5;        // 0..31
            int d4 = l & 31;
            ushort4 ku = *reinterpret_cast<const ushort4*>(kbase + (size_t)row * sk + 4 * d4);
            KsT[(4 * d4 + 0) * KP + row] = bu2f(ku.x);
            KsT[(4 * d4 + 1) * KP + row] = bu2f(ku.y);
            KsT[(4 * d4 + 2) * KP + row] = bu2f(ku.z);
            KsT[(4 * d4 + 3) * KP + row] = bu2f(ku.w);
            ushort4 vu = *reinterpret_cast<const ushort4*>(vbase + (size_t)row * sv + 4 * d4);
            float4 vv = make_float4(bu2f(vu.x), bu2f(vu.y), bu2f(vu.z), bu2f(vu.w));
            *reinterpret_cast<float4*>(&Vs[row * VP + 4 * d4]) = vv;
        }
        __syncthreads();

        // ---- QK^T: 4x2 scores per thread ----
        float s_[4][2] = {};
#pragma unroll 4
        for (int d = 0; d < HD; d++) {
            float4 aa = *reinterpret_cast<const float4*>(&QsT[d * QP + ty * 4]);
            float2 bb = *reinterpret_cast<const float2*>(&KsT[d * KP + tx * 2]);
            s_[0][0] += aa.x * bb.x; s_[0][1] += aa.x * bb.y;
            s_[1][0] += aa.y * bb.x; s_[1][1] += aa.y * bb.y;
            s_[2][0] += aa.z * bb.x; s_[2][1] += aa.z * bb.y;
            s_[3][0] += aa.w * bb.x; s_[3][1] += aa.w * bb.y;
        }
        bool diag = CAUSAL && (j0 + BK - 1 > q0);
#pragma unroll
        for (int i = 0; i < 4; i++) {
            int qi = q0 + ty * 4 + i;
#pragma unroll
            for (int j = 0; j < 2; j++) {
                float v = s_[i][j] * scale;
                if (diag && (j0 + tx * 2 + j > qi)) v = -1e30f;
                s_[i][j] = v;
            }
        }

        // ---- online softmax (per row: 16-lane butterfly) ----
        float alpha[4], pj0[4], pj1[4];
#pragma unroll
        for (int i = 0; i < 4; i++) {
            float rmax = fmaxf(s_[i][0], s_[i][1]);
#pragma unroll
            for (int mlane = 1; mlane < 16; mlane <<= 1)
                rmax = fmaxf(rmax, __shfl_xor(rmax, mlane));
            float mn = fmaxf(m_[i], rmax);
            float al = __expf(m_[i] - mn);
            float p0 = __expf(s_[i][0] - mn);
            float p1 = __expf(s_[i][1] - mn);
            float rs = p0 + p1;
#pragma unroll
            for (int mlane = 1; mlane < 16; mlane <<= 1) rs += __shfl_xor(rs, mlane);
            l_[i] = l_[i] * al + rs;
            m_[i] = mn;
            alpha[i] = al;
            pj0[i] = p0;
            pj1[i] = p1;
        }
        *reinterpret_cast<float4*>(&PsT[(tx * 2 + 0) * PP + ty * 4]) =
            make_float4(pj0[0], pj0[1], pj0[2], pj0[3]);
        *reinterpret_cast<float4*>(&PsT[(tx * 2 + 1) * PP + ty * 4]) =
            make_float4(pj1[0], pj1[1], pj1[2], pj1[3]);
        __syncthreads();

        // ---- PV accumulate: cols tx*4+c (c<4) and 64+tx*4+(c-4) (c>=4) ----
#pragma unroll
        for (int i = 0; i < 4; i++)
#pragma unroll
            for (int c = 0; c < 8; c++) o_[i][c] *= alpha[i];
#pragma unroll 2
        for (int j = 0; j < BK; j++) {
            float4 p4 = *reinterpret_cast<const float4*>(&PsT[j * PP + ty * 4]);
            float4 v0 = *reinterpret_cast<const float4*>(&Vs[j * VP + tx * 4]);
            float4 v1 = *reinterpret_cast<const float4*>(&Vs[j * VP + 64 + tx * 4]);
            float p_[4] = {p4.x, p4.y, p4.z, p4.w};
#pragma unroll
            for (int i = 0; i < 4; i++) {
                o_[i][0] += p_[i] * v0.x; o_[i][1] += p_[i] * v0.y;
                o_[i][2] += p_[i] * v0.z; o_[i][3] += p_[i] * v0.w;
                o_[i][4] += p_[i] * v1.x; o_[i][5] += p_[i] * v1.y;
                o_[i][6] += p_[i] * v1.z; o_[i][7] += p_[i] * v1.w;
            }
        }
    }

    // ---- finalize -> bf16 out (stride HID) ----
#pragma unroll
    for (int i = 0; i < 4; i++) {
        float inv = 1.f / l_[i];
        size_t base = (size_t)(q0 + ty * 4 + i) * HID + (size_t)h * HD;
        ushort4 o0, o1;
        o0.x = f2bu(o_[i][0] * inv); o0.y = f2bu(o_[i][1] * inv);
        o0.z = f2bu(o_[i][2] * inv); o0.w = f2bu(o_[i][3] * inv);
        o1.x = f2bu(o_[i][4] * inv); o1.y = f2bu(o_[i][5] * inv);
        o1.z = f2bu(o_[i][6] * inv); o1.w = f2bu(o_[i][7] * inv);
        *reinterpret_cast<ushort4*>(Out + base + tx * 4) = o0;
        *reinterpret_cast<ushort4*>(Out + base + 64 + tx * 4) = o1;
    }
}

// ---------------- f32 -> output dtype (per flag) ----------------
__global__ __launch_bounds__(256) void store_out_kernel(const float* __restrict__ a,
                                                        const float* __restrict__ b,
                                                        void* __restrict__ out,
                                                        const int* __restrict__ flag) {
    bool isbf = (*flag != 0);
    size_t i = (size_t)blockIdx.x * 256 + threadIdx.x;
    const size_t MM = (size_t)S * HID;
    float v = (i < MM) ? a[i] : b[i - MM];
    if (isbf)
        ((bf16*)out)[i] = __float2bfloat16(v);
    else
        ((float*)out)[i] = v;
}

extern "C" void kernel_launch(void* const* d_in, const int* in_sizes, int n_in,
                              void* d_out, int out_size, void* d_ws, size_t ws_size,
                              hipStream_t stream) {
    const void* x[2] = {d_in[0], d_in[1]};
    const void* w_ln[2] = {d_in[5], d_in[14]};
    const void* w_q[2] = {d_in[6], d_in[15]};
    const void* w_k[2] = {d_in[7], d_in[16]};
    const void* w_v[2] = {d_in[8], d_in[17]};
    const void* w_o[2] = {d_in[9], d_in[18]};
    const void* w_pln[2] = {d_in[10], d_in[19]};
    const void* w_g[2] = {d_in[11], d_in[20]};
    const void* w_u[2] = {d_in[12], d_in[21]};
    const void* w_d[2] = {d_in[13], d_in[22]};

    char* base = (char*)d_ws;
    int* flag = (int*)base;
    u16* p = (u16*)(base + 256);
    const size_t E_QKV = (size_t)S * 3072;   // 6.29M
    const size_t E_SH  = (size_t)S * HID;    // 2.10M
    const size_t E_GT  = (size_t)S * INTER;  // 8.39M

    u16* qkv[2] = {p, p + E_QKV};            p += 2 * E_QKV;
    u16* qr = p;                             p += E_SH;
    u16* kr = p;                             p += E_SH;
    u16* h_bf = p;                           p += E_SH;
    u16* attnbuf = p;                        p += E_SH;
    u16* gated = p;                          p += E_GT;   // mixed (4.2M) overlays gated
    u16* mixed = gated;
    u16* wqkvT = p;                          p += (size_t)3072 * 1024;
    u16* woT[2] = {p, p + (size_t)1024 * 1024};  p += 2 * (size_t)1024 * 1024;
    u16* wgT = p;                            p += (size_t)INTER * 1024;
    u16* wuT = p;                            p += (size_t)INTER * 1024;
    u16* wdT = p;                            p += (size_t)1024 * INTER;
    // align float region to 4B
    float* outX[2];
    float* fbase = (float*)(((size_t)p + 255) & ~(size_t)255);
    outX[0] = fbase;
    outX[1] = fbase + E_SH;

    probe_kernel<<<1, 256, 0, stream>>>((const unsigned short*)d_in[0], flag);

    for (int e = 0; e < 2; e++) {
        // weight transposes (bf16 B^T)
        transpose_w<<<dim3(1024 / 32, 1024 / 32), 256, 0, stream>>>(w_q[e], wqkvT, flag, 1024, 1024);
        transpose_w<<<dim3(1024 / 32, 1024 / 32), 256, 0, stream>>>(w_k[e], wqkvT + (size_t)1024 * 1024, flag, 1024, 1024);
        transpose_w<<<dim3(1024 / 32, 1024 / 32), 256, 0, stream>>>(w_v[e], wqkvT + (size_t)2048 * 1024, flag, 1024, 1024);
        transpose_w<<<dim3(1024 / 32, 1024 / 32), 256, 0, stream>>>(w_o[e], woT[e], flag, 1024, 1024);
        transpose_w<<<dim3(INTER / 32, 1024 / 32), 256, 0, stream>>>(w_g[e], wgT, flag, 1024, INTER);
        transpose_w<<<dim3(INTER / 32, 1024 / 32), 256, 0, stream>>>(w_u[e], wuT, flag, 1024, INTER);
        transpose_w<<<dim3(1024 / 32, INTER / 32), 256, 0, stream>>>(w_d[e], wdT, flag, INTER, 1024);

        rmsnorm_kernel<<<S, 256, 0, stream>>>(x[e], w_ln[e], h_bf, flag, 1);
        // fused QKV: (2048x1024) @ (1024x3072) -> qkv[e]
        gemm_mfma<128, 128, 2, 2, 0><<<dim3(3072 / 128, S / 128), 256, 0, stream>>>(
            h_bf, wqkvT, nullptr, qkv[e], nullptr, flag, S, 3072, 1024);
        rope_kernel<<<S * NH, 64, 0, stream>>>(qkv[e], qr, kr);
        attn_tiled_kernel<true><<<dim3(S / 64, NH), 256, 0, stream>>>(
            qr, qr, HID, kr, kr, HID, qkv[e] + 2048, qkv[e] + 2048, 3072, attnbuf, S);
        gemm_mfma<64, 128, 1, 4, 1><<<dim3(1024 / 128, S / 64), 256, 0, stream>>>(
            attnbuf, woT[e], outX[e], nullptr, x[e], flag, S, 1024, 1024);
        rmsnorm_kernel<<<S, 256, 0, stream>>>(outX[e], w_pln[e], h_bf, flag, 0);
        gemm_gated_mfma<128, 64, 2, 2><<<dim3(INTER / 64, S / 128), 256, 0, stream>>>(
            h_bf, wgT, wuT, gated, S, INTER, 1024);
        gemm_mfma<64, 128, 1, 4, 2><<<dim3(1024 / 128, S / 64), 256, 0, stream>>>(
            gated, wdT, outX[e], nullptr, nullptr, flag, S, 1024, INTER);
    }

    attn_tiled_kernel<false><<<dim3(2 * S / 64, NH), 256, 0, stream>>>(
        qkv[0], qkv[1], 3072, qkv[0] + 1024, qkv[1] + 1024, 3072,
        qkv[0] + 2048, qkv[1] + 2048, 3072, mixed, 2 * S);
    gemm_mfma<64, 128, 1, 4, 2><<<dim3(1024 / 128, S / 64), 256, 0, stream>>>(
        mixed, woT[0], outX[0], nullptr, nullptr, flag, S, 1024, 1024);
    gemm_mfma<64, 128, 1, 4, 2><<<dim3(1024 / 128, S / 64), 256, 0, stream>>>(
        mixed + (size_t)S * HID, woT[1], outX[1], nullptr, nullptr, flag, S, 1024, 1024);

    store_out_kernel<<<(2 * (size_t)S * HID) / 256, 256, 0, stream>>>(outX[0], outX[1], d_out, flag);
}

// Round 5
// 1348.189 us; speedup vs baseline: 10.8384x; 2.2234x over previous
//
#include <hip/hip_runtime.h>
#include <hip/hip_bf16.h>
#include <math.h>

#define S 2048
#define HID 1024
#define NH 8
#define HD 128
#define INTER 4096
#define EPSV 1e-6f
#define THETA 10000.0f

typedef __hip_bfloat16 bf16;
typedef unsigned short u16;
typedef __attribute__((ext_vector_type(8))) short bf16x8;  // 8 bf16 = 4 VGPRs
typedef __attribute__((ext_vector_type(4))) float f32x4;

__device__ inline float bu2f(u16 u) {
    unsigned int x = ((unsigned int)u) << 16;
    return __uint_as_float(x);
}
__device__ inline u16 f2bu(float f) {
    bf16 h = __float2bfloat16(f);
    return *reinterpret_cast<u16*>(&h);
}
// Dual-dtype input load (raw harness inputs): isbf ? bf16 : f32
__device__ inline float ldin(const void* p, size_t i, bool isbf) {
    return isbf ? bu2f(((const u16*)p)[i]) : ((const float*)p)[i];
}
__device__ inline float gelu_tanh(float x) {
    float x3 = x * x * x;
    return 0.5f * x * (1.f + tanhf(0.7978845608028654f * (x + 0.044715f * x3)));
}

// ---------------- dtype probe (round-1 notes) ----------------
__global__ __launch_bounds__(256) void probe_kernel(const unsigned short* __restrict__ x,
                                                    int* __restrict__ flag) {
    __shared__ int red[256];
    int tid = threadIdx.x;
    int cnt = 0;
    for (int i = tid; i < 2048; i += 256) {
        unsigned short u = x[2 * i];
        int e = (u >> 7) & 0xFF;
        cnt += (e >= 110 && e <= 135) ? 1 : 0;
    }
    red[tid] = cnt;
    __syncthreads();
    for (int off = 128; off > 0; off >>= 1) {
        if (tid < off) red[tid] += red[tid + off];
        __syncthreads();
    }
    if (tid == 0) *flag = (red[0] > 1024) ? 1 : 0;
}

// ---------------- weight transpose+convert: W (KxN, input dtype) -> WT (NxK, bf16) ----------------
__global__ __launch_bounds__(256) void transpose_w(const void* __restrict__ W,
                                                   u16* __restrict__ WT,
                                                   const int* __restrict__ flag,
                                                   int K, int N) {
    bool isbf = (*flag != 0);
    __shared__ float t[32][33];
    int n0 = blockIdx.x * 32, k0 = blockIdx.y * 32;
    int c = threadIdx.x & 31, r = threadIdx.x >> 5;
#pragma unroll
    for (int p = 0; p < 4; p++)
        t[r + 8 * p][c] = ldin(W, (size_t)(k0 + r + 8 * p) * N + n0 + c, isbf);
    __syncthreads();
#pragma unroll
    for (int p = 0; p < 4; p++) {
        int row = r + 8 * p;
        WT[(size_t)(n0 + row) * K + k0 + c] = f2bu(t[c][row]);
    }
}

// ---------------- V transpose: V[key][dh] (stride sv, bf16) -> VT[dh][key] (2048 keys) ----------------
__global__ __launch_bounds__(256) void transpose_v(const u16* __restrict__ V, int sv,
                                                   u16* __restrict__ VT) {
    __shared__ u16 t[32][33];
    int k0 = blockIdx.x * 32;  // key tile
    int d0 = blockIdx.y * 32;  // dh tile
    int c = threadIdx.x & 31, r = threadIdx.x >> 5;
#pragma unroll
    for (int p = 0; p < 4; p++)
        t[r + 8 * p][c] = V[(size_t)(k0 + r + 8 * p) * sv + d0 + c];
    __syncthreads();
#pragma unroll
    for (int p = 0; p < 4; p++)
        VT[(size_t)(d0 + r + 8 * p) * S + k0 + c] = t[c][r + 8 * p];
}

// ---------------- RMSNorm -> bf16 ----------------
__global__ __launch_bounds__(256) void rmsnorm_kernel(const void* __restrict__ x,
                                                      const void* __restrict__ w,
                                                      u16* __restrict__ y,
                                                      const int* __restrict__ flag,
                                                      int dual) {
    bool isbf = (*flag != 0);
    bool xbf = dual && isbf;
    int row = blockIdx.x;
    size_t base = (size_t)row * HID;
    __shared__ float red[256];
    float xv[4];
    float s = 0.f;
#pragma unroll
    for (int i = 0; i < 4; i++) {
        float v = ldin(x, base + threadIdx.x + 256 * i, xbf);
        xv[i] = v;
        s += v * v;
    }
    red[threadIdx.x] = s;
    __syncthreads();
    for (int off = 128; off > 0; off >>= 1) {
        if (threadIdx.x < off) red[threadIdx.x] += red[threadIdx.x + off];
        __syncthreads();
    }
    float scale = rsqrtf(red[0] / (float)HID + EPSV);
#pragma unroll
    for (int i = 0; i < 4; i++) {
        int c = threadIdx.x + 256 * i;
        y[base + c] = f2bu(xv[i] * scale * (1.f + ldin(w, c, isbf)));
    }
}

// ================= MFMA GEMM (verified round 4) =================
template <int BM, int BN, int WRN, int WCN, int EPI>
__global__ __launch_bounds__(256) void gemm_mfma(const u16* __restrict__ A,
                                                 const u16* __restrict__ BT,
                                                 float* __restrict__ Cf,
                                                 u16* __restrict__ Cb,
                                                 const void* __restrict__ res,
                                                 const int* __restrict__ flag,
                                                 int M, int N, int K) {
    constexpr int BK = 32, LDK = 40;
    constexpr int WM = BM / WRN, WN = BN / WCN, TI = WM / 16, TJ = WN / 16;
    constexpr int AIT = BM / 64, BIT = BN / 64;
    __shared__ u16 As[BM * LDK];
    __shared__ u16 Bs[BN * LDK];
    int tid = threadIdx.x, lane = tid & 63, wv = tid >> 6;
    int wr = wv / WCN, wc = wv % WCN;
    int m = lane & 15, quad = lane >> 4;
    int m0 = blockIdx.y * BM, n0 = blockIdx.x * BN;
    f32x4 acc[TI][TJ] = {};
    for (int k0 = 0; k0 < K; k0 += BK) {
        __syncthreads();
#pragma unroll
        for (int i = 0; i < AIT; i++) {
            int l = tid + 256 * i;
            int row = l >> 2, kq = l & 3;
            *reinterpret_cast<uint4*>(&As[row * LDK + kq * 8]) =
                *reinterpret_cast<const uint4*>(&A[(size_t)(m0 + row) * K + k0 + kq * 8]);
        }
#pragma unroll
        for (int i = 0; i < BIT; i++) {
            int l = tid + 256 * i;
            int row = l >> 2, kq = l & 3;
            *reinterpret_cast<uint4*>(&Bs[row * LDK + kq * 8]) =
                *reinterpret_cast<const uint4*>(&BT[(size_t)(n0 + row) * K + k0 + kq * 8]);
        }
        __syncthreads();
        bf16x8 af[TI], bf_[TJ];
#pragma unroll
        for (int i = 0; i < TI; i++)
            af[i] = *reinterpret_cast<const bf16x8*>(&As[(wr * WM + i * 16 + m) * LDK + quad * 8]);
#pragma unroll
        for (int j = 0; j < TJ; j++)
            bf_[j] = *reinterpret_cast<const bf16x8*>(&Bs[(wc * WN + j * 16 + m) * LDK + quad * 8]);
#pragma unroll
        for (int i = 0; i < TI; i++)
#pragma unroll
            for (int j = 0; j < TJ; j++)
                acc[i][j] = __builtin_amdgcn_mfma_f32_16x16x32_bf16(af[i], bf_[j], acc[i][j], 0, 0, 0);
    }
    bool isbf = (EPI == 1) ? (*flag != 0) : false;
#pragma unroll
    for (int i = 0; i < TI; i++) {
#pragma unroll
        for (int j = 0; j < TJ; j++) {
#pragma unroll
            for (int r = 0; r < 4; r++) {
                int row = m0 + wr * WM + i * 16 + quad * 4 + r;
                int col = n0 + wc * WN + j * 16 + m;
                size_t idx = (size_t)row * N + col;
                float v = acc[i][j][r];
                if (EPI == 0) Cb[idx] = f2bu(v);
                else if (EPI == 1) Cf[idx] = v + ldin(res, idx, isbf);
                else Cf[idx] = Cf[idx] + v;
            }
        }
    }
}

// ------------- Fused gated MLP MFMA: C(bf16) = gelu(A@Wg) * (A@Wu) -------------
template <int BM, int BN, int WRN, int WCN>
__global__ __launch_bounds__(256) void gemm_gated_mfma(const u16* __restrict__ A,
                                                       const u16* __restrict__ BgT,
                                                       const u16* __restrict__ BuT,
                                                       u16* __restrict__ C,
                                                       int M, int N, int K) {
    constexpr int BK = 32, LDK = 40;
    constexpr int WM = BM / WRN, WN = BN / WCN, TI = WM / 16, TJ = WN / 16;
    constexpr int AIT = BM / 64, BIT = BN / 64;
    __shared__ u16 As[BM * LDK];
    __shared__ u16 Bgs[BN * LDK];
    __shared__ u16 Bus[BN * LDK];
    int tid = threadIdx.x, lane = tid & 63, wv = tid >> 6;
    int wr = wv / WCN, wc = wv % WCN;
    int m = lane & 15, quad = lane >> 4;
    int m0 = blockIdx.y * BM, n0 = blockIdx.x * BN;
    f32x4 accg[TI][TJ] = {};
    f32x4 accu[TI][TJ] = {};
    for (int k0 = 0; k0 < K; k0 += BK) {
        __syncthreads();
#pragma unroll
        for (int i = 0; i < AIT; i++) {
            int l = tid + 256 * i;
            int row = l >> 2, kq = l & 3;
            *reinterpret_cast<uint4*>(&As[row * LDK + kq * 8]) =
                *reinterpret_cast<const uint4*>(&A[(size_t)(m0 + row) * K + k0 + kq * 8]);
        }
#pragma unroll
        for (int i = 0; i < BIT; i++) {
            int l = tid + 256 * i;
            int row = l >> 2, kq = l & 3;
            *reinterpret_cast<uint4*>(&Bgs[row * LDK + kq * 8]) =
                *reinterpret_cast<const uint4*>(&BgT[(size_t)(n0 + row) * K + k0 + kq * 8]);
            *reinterpret_cast<uint4*>(&Bus[row * LDK + kq * 8]) =
                *reinterpret_cast<const uint4*>(&BuT[(size_t)(n0 + row) * K + k0 + kq * 8]);
        }
        __syncthreads();
        bf16x8 af[TI], bg[TJ], bu[TJ];
#pragma unroll
        for (int i = 0; i < TI; i++)
            af[i] = *reinterpret_cast<const bf16x8*>(&As[(wr * WM + i * 16 + m) * LDK + quad * 8]);
#pragma unroll
        for (int j = 0; j < TJ; j++) {
            bg[j] = *reinterpret_cast<const bf16x8*>(&Bgs[(wc * WN + j * 16 + m) * LDK + quad * 8]);
            bu[j] = *reinterpret_cast<const bf16x8*>(&Bus[(wc * WN + j * 16 + m) * LDK + quad * 8]);
        }
#pragma unroll
        for (int i = 0; i < TI; i++)
#pragma unroll
            for (int j = 0; j < TJ; j++) {
                accg[i][j] = __builtin_amdgcn_mfma_f32_16x16x32_bf16(af[i], bg[j], accg[i][j], 0, 0, 0);
                accu[i][j] = __builtin_amdgcn_mfma_f32_16x16x32_bf16(af[i], bu[j], accu[i][j], 0, 0, 0);
            }
    }
#pragma unroll
    for (int i = 0; i < TI; i++)
#pragma unroll
        for (int j = 0; j < TJ; j++)
#pragma unroll
            for (int r = 0; r < 4; r++) {
                int row = m0 + wr * WM + i * 16 + quad * 4 + r;
                int col = n0 + wc * WN + j * 16 + m;
                C[(size_t)row * N + col] = f2bu(gelu_tanh(accg[i][j][r]) * accu[i][j][r]);
            }
}

// ---------------- RoPE: read qkv (bf16, stride 3072), write qr/kr (bf16, stride 1024) ----------------
__global__ __launch_bounds__(64) void rope_kernel(const u16* __restrict__ qkv,
                                                  u16* __restrict__ qr,
                                                  u16* __restrict__ kr) {
    int b = blockIdx.x;
    int t = b >> 3, h = b & 7;
    int i = threadIdx.x;  // 0..63
    size_t ib = (size_t)t * 3072 + h * HD;
    size_t ob = (size_t)t * HID + h * HD;
    float inv = powf(THETA, -(float)(2 * i) / (float)HD);
    float f = (float)t * inv;
    float c = cosf(f), s = sinf(f);
    float q1 = bu2f(qkv[ib + i]), q2 = bu2f(qkv[ib + i + 64]);
    qr[ob + i] = f2bu(q1 * c - q2 * s);
    qr[ob + i + 64] = f2bu(q2 * c + q1 * s);
    float k1 = bu2f(qkv[ib + 1024 + i]), k2 = bu2f(qkv[ib + 1024 + i + 64]);
    kr[ob + i] = f2bu(k1 * c - k2 * s);
    kr[ob + i + 64] = f2bu(k2 * c + k1 * s);
}

// ============ MFMA flash attention ============
// Block: 64 queries x 1 head; 4 waves, wave w owns q-rows 16w..16w+15.
// 64-key tiles. QK^T and PV via mfma_f32_16x16x32_bf16 with the round-4-verified
// fragment mapping (a-frag: M-rows [lane&15][quad*8+j]; b-frag: B^T rows;
// C/D: row=quad*4+r, col=lane&15). P round-trips through LDS (C-layout ->
// a-frag layout). V comes pre-transposed in global (VT[dh][key]) so staging is
// coalesced + conflict-free. K staged in GEMM-proven [kstep][row][40] layout.
template <bool CAUSAL>
__global__ __launch_bounds__(256) void attn_mfma_kernel(
    const u16* __restrict__ qa, const u16* __restrict__ qb, int sq,
    const u16* __restrict__ ka, const u16* __restrict__ kb, int sk,
    const u16* __restrict__ vta, const u16* __restrict__ vtb,
    u16* __restrict__ Out, int nkeys) {
    __shared__ u16 Ks[4][64][40];    // [d-step t][key][8*kq within 32-d]
    __shared__ u16 VTs[2][128][40];  // [key-step ks][d][8*kq within 32-key]
    __shared__ u16 Ps[64][72];       // [q][key] bf16, 144B rows

    int tid = threadIdx.x;
    int lane = tid & 63, w = tid >> 6;
    int col = lane & 15, quad = lane >> 4;
    int q0 = blockIdx.x * 64;
    int h = blockIdx.y;
    const float scale = 0.08838834764831845f;  // 1/sqrt(128)

    // Q a-frags (4 d-steps of 32) straight from global into registers
    int q0r = CAUSAL ? q0 : (q0 & (S - 1));
    const u16* qp = ((CAUSAL || q0 < S) ? qa : qb) + (size_t)q0r * sq;
    bf16x8 aq[4];
#pragma unroll
    for (int t = 0; t < 4; t++)
        aq[t] = *reinterpret_cast<const bf16x8*>(
            qp + (size_t)(16 * w + col) * sq + h * HD + 32 * t + quad * 8);

    f32x4 o[8] = {};
    float m_[4], l_[4];
#pragma unroll
    for (int r = 0; r < 4; r++) {
        m_[r] = -1e30f;
        l_[r] = 0.f;
    }

    int ntiles = CAUSAL ? (q0 >> 6) + 1 : (nkeys >> 6);
    for (int tt = 0; tt < ntiles; tt++) {
        int j0 = tt * 64;
        int j0r = j0 & (S - 1);
        bool eb = (!CAUSAL) && (j0 >= S);
        const u16* kp = eb ? kb : ka;
        const u16* vp = eb ? vtb : vta;
        __syncthreads();  // prev iter's compute done before restaging
        // ---- stage K tile: 64 keys x 128 d ----
#pragma unroll
        for (int i = 0; i < 4; i++) {
            int l = tid + 256 * i;
            int key = l >> 4, c = l & 15;
            int t = c >> 2, kq = c & 3;
            *reinterpret_cast<uint4*>(&Ks[t][key][kq * 8]) =
                *reinterpret_cast<const uint4*>(kp + (size_t)(j0r + key) * sk + h * HD + c * 8);
        }
        // ---- stage V^T tile: 128 d x 64 keys ----
#pragma unroll
        for (int i = 0; i < 4; i++) {
            int l = tid + 256 * i;
            int d = l >> 3, c = l & 7;
            int ks = c >> 2, kq = c & 3;
            *reinterpret_cast<uint4*>(&VTs[ks][d][kq * 8]) =
                *reinterpret_cast<const uint4*>(vp + (size_t)(h * HD + d) * S + j0r + c * 8);
        }
        __syncthreads();

        // ---- QK^T: wave computes 16q x 64k (4 col-tiles) ----
        f32x4 sc[4] = {};
#pragma unroll
        for (int t = 0; t < 4; t++) {
#pragma unroll
            for (int ct = 0; ct < 4; ct++) {
                bf16x8 kb_ = *reinterpret_cast<const bf16x8*>(&Ks[t][16 * ct + col][quad * 8]);
                sc[ct] = __builtin_amdgcn_mfma_f32_16x16x32_bf16(aq[t], kb_, sc[ct], 0, 0, 0);
            }
        }
        bool diag = CAUSAL && (j0 == q0);
#pragma unroll
        for (int ct = 0; ct < 4; ct++) {
#pragma unroll
            for (int r = 0; r < 4; r++) {
                float v = sc[ct][r] * scale;
                if (diag && (16 * ct + col > 16 * w + 4 * quad + r)) v = -1e30f;
                sc[ct][r] = v;
            }
        }

        // ---- online softmax on C-layout rows (16-lane butterflies) ----
        float alpha[4];
#pragma unroll
        for (int r = 0; r < 4; r++) {
            float rmax = fmaxf(fmaxf(sc[0][r], sc[1][r]), fmaxf(sc[2][r], sc[3][r]));
#pragma unroll
            for (int mk = 1; mk < 16; mk <<= 1) rmax = fmaxf(rmax, __shfl_xor(rmax, mk));
            float mn = fmaxf(m_[r], rmax);
            float al = __expf(m_[r] - mn);
            float p0 = __expf(sc[0][r] - mn);
            float p1 = __expf(sc[1][r] - mn);
            float p2 = __expf(sc[2][r] - mn);
            float p3 = __expf(sc[3][r] - mn);
            float rs = (p0 + p1) + (p2 + p3);
#pragma unroll
            for (int mk = 1; mk < 16; mk <<= 1) rs += __shfl_xor(rs, mk);
            l_[r] = l_[r] * al + rs;
            m_[r] = mn;
            alpha[r] = al;
            int prow = 16 * w + 4 * quad + r;
            Ps[prow][col] = f2bu(p0);
            Ps[prow][16 + col] = f2bu(p1);
            Ps[prow][32 + col] = f2bu(p2);
            Ps[prow][48 + col] = f2bu(p3);
        }
        // (Ps RAW is wave-local; compiler inserts lgkmcnt before the reads)

        // ---- PV: O = diag(alpha)*O + P @ V ----
#pragma unroll
        for (int nt = 0; nt < 8; nt++)
#pragma unroll
            for (int r = 0; r < 4; r++) o[nt][r] *= alpha[r];
#pragma unroll
        for (int ks = 0; ks < 2; ks++) {
            bf16x8 pa = *reinterpret_cast<const bf16x8*>(&Ps[16 * w + col][32 * ks + quad * 8]);
#pragma unroll
            for (int nt = 0; nt < 8; nt++) {
                bf16x8 vb_ = *reinterpret_cast<const bf16x8*>(&VTs[ks][16 * nt + col][quad * 8]);
                o[nt] = __builtin_amdgcn_mfma_f32_16x16x32_bf16(pa, vb_, o[nt], 0, 0, 0);
            }
        }
    }

    // ---- epilogue: O /= l, write bf16 (stride HID) ----
#pragma unroll
    for (int r = 0; r < 4; r++) {
        float inv = 1.f / l_[r];
        size_t rowoff = (size_t)(q0 + 16 * w + 4 * quad + r) * HID + (size_t)h * HD;
#pragma unroll
        for (int nt = 0; nt < 8; nt++)
            Out[rowoff + 16 * nt + col] = f2bu(o[nt][r] * inv);
    }
}

// ---------------- f32 -> output dtype (per flag) ----------------
__global__ __launch_bounds__(256) void store_out_kernel(const float* __restrict__ a,
                                                        const float* __restrict__ b,
                                                        void* __restrict__ out,
                                                        const int* __restrict__ flag) {
    bool isbf = (*flag != 0);
    size_t i = (size_t)blockIdx.x * 256 + threadIdx.x;
    const size_t MM = (size_t)S * HID;
    float v = (i < MM) ? a[i] : b[i - MM];
    if (isbf)
        ((bf16*)out)[i] = __float2bfloat16(v);
    else
        ((float*)out)[i] = v;
}

extern "C" void kernel_launch(void* const* d_in, const int* in_sizes, int n_in,
                              void* d_out, int out_size, void* d_ws, size_t ws_size,
                              hipStream_t stream) {
    const void* x[2] = {d_in[0], d_in[1]};
    const void* w_ln[2] = {d_in[5], d_in[14]};
    const void* w_q[2] = {d_in[6], d_in[15]};
    const void* w_k[2] = {d_in[7], d_in[16]};
    const void* w_v[2] = {d_in[8], d_in[17]};
    const void* w_o[2] = {d_in[9], d_in[18]};
    const void* w_pln[2] = {d_in[10], d_in[19]};
    const void* w_g[2] = {d_in[11], d_in[20]};
    const void* w_u[2] = {d_in[12], d_in[21]};
    const void* w_d[2] = {d_in[13], d_in[22]};

    char* base = (char*)d_ws;
    int* flag = (int*)base;
    u16* p = (u16*)(base + 256);
    const size_t E_QKV = (size_t)S * 3072;
    const size_t E_SH = (size_t)S * HID;
    const size_t E_GT = (size_t)S * INTER;
    const size_t E_VT = (size_t)NH * HD * S;  // 2.1M u16 per expert

    u16* qkv[2] = {p, p + E_QKV};            p += 2 * E_QKV;
    u16* qr = p;                             p += E_SH;
    u16* kr = p;                             p += E_SH;
    u16* h_bf = p;                           p += E_SH;
    u16* attnbuf = p;                        p += E_SH;
    u16* vtg[2] = {p, p + E_VT};             p += 2 * E_VT;
    u16* gated = p;                          p += E_GT;  // mixed overlays gated
    u16* mixed = gated;
    u16* wqkvT = p;                          p += (size_t)3072 * 1024;
    u16* woT[2] = {p, p + (size_t)1024 * 1024};  p += 2 * (size_t)1024 * 1024;
    u16* wgT = p;                            p += (size_t)INTER * 1024;
    u16* wuT = p;                            p += (size_t)INTER * 1024;
    u16* wdT = p;                            p += (size_t)1024 * INTER;
    float* fbase = (float*)(((size_t)p + 255) & ~(size_t)255);
    float* outX[2] = {fbase, fbase + E_SH};

    probe_kernel<<<1, 256, 0, stream>>>((const unsigned short*)d_in[0], flag);

    for (int e = 0; e < 2; e++) {
        transpose_w<<<dim3(1024 / 32, 1024 / 32), 256, 0, stream>>>(w_q[e], wqkvT, flag, 1024, 1024);
        transpose_w<<<dim3(1024 / 32, 1024 / 32), 256, 0, stream>>>(w_k[e], wqkvT + (size_t)1024 * 1024, flag, 1024, 1024);
        transpose_w<<<dim3(1024 / 32, 1024 / 32), 256, 0, stream>>>(w_v[e], wqkvT + (size_t)2048 * 1024, flag, 1024, 1024);
        transpose_w<<<dim3(1024 / 32, 1024 / 32), 256, 0, stream>>>(w_o[e], woT[e], flag, 1024, 1024);
        transpose_w<<<dim3(INTER / 32, 1024 / 32), 256, 0, stream>>>(w_g[e], wgT, flag, 1024, INTER);
        transpose_w<<<dim3(INTER / 32, 1024 / 32), 256, 0, stream>>>(w_u[e], wuT, flag, 1024, INTER);
        transpose_w<<<dim3(1024 / 32, INTER / 32), 256, 0, stream>>>(w_d[e], wdT, flag, INTER, 1024);

        rmsnorm_kernel<<<S, 256, 0, stream>>>(x[e], w_ln[e], h_bf, flag, 1);
        gemm_mfma<128, 128, 2, 2, 0><<<dim3(3072 / 128, S / 128), 256, 0, stream>>>(
            h_bf, wqkvT, nullptr, qkv[e], nullptr, flag, S, 3072, 1024);
        rope_kernel<<<S * NH, 64, 0, stream>>>(qkv[e], qr, kr);
        transpose_v<<<dim3(S / 32, 1024 / 32), 256, 0, stream>>>(qkv[e] + 2048, 3072, vtg[e]);
        attn_mfma_kernel<true><<<dim3(S / 64, NH), 256, 0, stream>>>(
            qr, qr, HID, kr, kr, HID, vtg[e], vtg[e], attnbuf, S);
        gemm_mfma<64, 128, 1, 4, 1><<<dim3(1024 / 128, S / 64), 256, 0, stream>>>(
            attnbuf, woT[e], outX[e], nullptr, x[e], flag, S, 1024, 1024);
        rmsnorm_kernel<<<S, 256, 0, stream>>>(outX[e], w_pln[e], h_bf, flag, 0);
        gemm_gated_mfma<128, 64, 2, 2><<<dim3(INTER / 64, S / 128), 256, 0, stream>>>(
            h_bf, wgT, wuT, gated, S, INTER, 1024);
        gemm_mfma<64, 128, 1, 4, 2><<<dim3(1024 / 128, S / 64), 256, 0, stream>>>(
            gated, wdT, outX[e], nullptr, nullptr, flag, S, 1024, INTER);
    }

    attn_mfma_kernel<false><<<dim3(2 * S / 64, NH), 256, 0, stream>>>(
        qkv[0], qkv[1], 3072, qkv[0] + 1024, qkv[1] + 1024, 3072,
        vtg[0], vtg[1], mixed, 2 * S);
    gemm_mfma<64, 128, 1, 4, 2><<<dim3(1024 / 128, S / 64), 256, 0, stream>>>(
        mixed, woT[0], outX[0], nullptr, nullptr, flag, S, 1024, 1024);
    gemm_mfma<64, 128, 1, 4, 2><<<dim3(1024 / 128, S / 64), 256, 0, stream>>>(
        mixed + E_SH, woT[1], outX[1], nullptr, nullptr, flag, S, 1024, 1024);

    store_out_kernel<<<(2 * E_SH) / 256, 256, 0, stream>>>(outX[0], outX[1], d_out, flag);
}